// Round 5
// baseline (801.914 us; speedup 1.0000x reference)
//
#include <hip/hip_runtime.h>

#define HH   6
#define NN   343
#define BB   512
#define DIMC 192
#define MM   (BB*NN)      // 175616

// workspace offsets (bytes)
#define OFF_TABLE 0                        // [2197][8] f32
#define OFF_R     70400                    // [6][343][352] f32  (exp(rpb-26), zero tail)
#define OFF_MB    2968064                  // [64*343][16] u32   (bit-packed mask, lane-repacked)
#define OFF_QB    4372992                  // [M][192] bf16 (normalized * scale * log2e)
#define OFF_KB    (OFF_QB + 67436544)      // [M][192] bf16 (normalized)
#define OFF_VB    (OFF_KB + 67436544)
#define OFF_CROSS (OFF_VB + 67436544)
#define OFF_WB    (OFF_CROSS + 67436544)   // [1344][192] bf16: qkv1(576), qkv2(576), proj(192)
// end = 274,635,264 bytes

typedef __bf16 bf16x8 __attribute__((ext_vector_type(8)));
typedef float  f32x4  __attribute__((ext_vector_type(4)));

__device__ __forceinline__ f32x4 mfma16(bf16x8 a, bf16x8 b, f32x4 c) {
    return __builtin_amdgcn_mfma_f32_16x16x32_bf16(a, b, c, 0, 0, 0);
}

__device__ __forceinline__ unsigned pack2(float a, float b) {
    union { __bf16 h[2]; unsigned u; } x;
    x.h[0] = (__bf16)a; x.h[1] = (__bf16)b;
    return x.u;
}

// ---------------- K1: CPB MLP -> table[2197][8] ----------------
__global__ __launch_bounds__(256) void cpb_table_kernel(
    const float* __restrict__ rel_table, const float* __restrict__ w1,
    const float* __restrict__ b1, const float* __restrict__ w2,
    float* __restrict__ table)
{
    int i = blockIdx.x;
    int t = threadIdx.x;
    float t0 = rel_table[i*3+0], t1 = rel_table[i*3+1], t2 = rel_table[i*3+2];
    float acc[HH];
    #pragma unroll
    for (int h = 0; h < HH; h++) acc[h] = 0.f;
    for (int j = t; j < 512; j += 256) {
        float hv = w1[j*3+0]*t0 + w1[j*3+1]*t1 + w1[j*3+2]*t2 + b1[j];
        hv = fmaxf(hv, 0.f);
        #pragma unroll
        for (int h = 0; h < HH; h++) acc[h] += w2[h*512+j] * hv;
    }
    __shared__ float red[256*HH];
    #pragma unroll
    for (int h = 0; h < HH; h++) red[t*HH+h] = acc[h];
    __syncthreads();
    for (int s = 128; s > 0; s >>= 1) {
        if (t < s) {
            #pragma unroll
            for (int h = 0; h < HH; h++) red[t*HH+h] += red[(t+s)*HH+h];
        }
        __syncthreads();
    }
    if (t < HH) table[(size_t)i*8 + t] = red[t];
}

// ---------------- K2: R = exp(16*sigmoid(gather) - 26), [6][343][352] ----------------
__global__ __launch_bounds__(256) void r_kernel(
    const float* __restrict__ table, const int* __restrict__ rp_index,
    float* __restrict__ R)
{
    int id = blockIdx.x*256 + threadIdx.x;
    if (id >= HH*NN*352) return;
    int h   = id / (NN*352);
    int rem = id - h*(NN*352);
    int n   = rem / 352;
    int mc  = rem - n*352;
    float out = 0.f;
    if (mc < NN) {
        float v = table[(size_t)rp_index[n*NN+mc]*8 + h];
        float r = 16.f / (1.f + __expf(-v));
        out = __expf(r - 26.f);
    }
    R[id] = out;
}

// ---------------- K3: bit-pack mask, lane-stream layout ----------------
__global__ __launch_bounds__(256) void mbits_kernel(
    const float* __restrict__ mask, unsigned* __restrict__ mb)
{
    int id  = blockIdx.x*256 + threadIdx.x;   // 64*343*4 threads
    int lg  = id & 3;
    int row = id >> 2;                         // w*343 + n
    const float* mrow = mask + (size_t)row*NN;
    unsigned out[3];
    #pragma unroll
    for (int t = 0; t < 3; t++) {
        unsigned u = 0;
        #pragma unroll
        for (int bb = 0; bb < 32; bb++) {
            int mt = 8*t + (bb>>2), r = bb & 3;
            int m  = 16*mt + 4*lg + r;
            if (m < NN && mrow[m] > -50.f) u |= (1u << bb);
        }
        out[t] = u;
    }
    *(uint4*)(mb + (size_t)row*16 + 4*lg) = make_uint4(out[0], out[1], out[2], 0u);
}

// ---------------- K4: convert weights f32 -> bf16 (qkv1 | qkv2 | proj) ----------------
__global__ __launch_bounds__(256) void wcvt_kernel(
    const float* __restrict__ qkv1, const float* __restrict__ qkv2,
    const float* __restrict__ proj, __bf16* __restrict__ out)
{
    int i = blockIdx.x*256 + threadIdx.x;   // float4 index
    const int n1 = 110592/4, n2 = 221184/4, n3 = 258048/4;
    if (i >= n3) return;
    const float* src; int off;
    if (i < n1)      { src = qkv1; off = i; }
    else if (i < n2) { src = qkv2; off = i - n1; }
    else             { src = proj; off = i - n2; }
    float4 v = ((const float4*)src)[off];
    __bf16* d = out + (size_t)i*4;
    d[0] = (__bf16)v.x; d[1] = (__bf16)v.y; d[2] = (__bf16)v.z; d[3] = (__bf16)v.w;
}

// ---------------- GEMM: f32 in, bf16 W direct from L2, no LDS, up to 2 phases ----------------
// norm: 0 = none, 1 = k-norm (1/|k|), 2 = q-norm (scale*log2e/|q|)
__global__ __launch_bounds__(256) void gemm_f32in(
    const float* __restrict__ A, const float* __restrict__ ls,
    const __bf16* __restrict__ W0, const float* __restrict__ bias0, int norm0, __bf16* __restrict__ D0,
    const __bf16* __restrict__ W1, const float* __restrict__ bias1, int norm1, __bf16* __restrict__ D1)
{
    int m0 = blockIdx.x * 64;
    int t  = threadIdx.x;
    int wave = t >> 6, lane = t & 63, lr = lane & 15, lg = lane >> 4;
    int r = m0 + 16*wave + lr;

    // A row fragments, f32 -> bf16, kept in regs across phases
    bf16x8 afr[6];
    #pragma unroll
    for (int ks = 0; ks < 6; ks++) {
        const float* ap = A + (size_t)r*DIMC + 32*ks + 8*lg;
        float4 v0 = *(const float4*)ap;
        float4 v1 = *(const float4*)(ap + 4);
        bf16x8 f;
        f[0]=(__bf16)v0.x; f[1]=(__bf16)v0.y; f[2]=(__bf16)v0.z; f[3]=(__bf16)v0.w;
        f[4]=(__bf16)v1.x; f[5]=(__bf16)v1.y; f[6]=(__bf16)v1.z; f[7]=(__bf16)v1.w;
        afr[ks] = f;
    }

    #pragma unroll 1
    for (int phase = 0; phase < 2; phase++) {
        const __bf16* W    = phase ? W1 : W0;
        if (!W) break;
        const float* bias  = phase ? bias1 : bias0;
        int          nrm   = phase ? norm1 : norm0;
        __bf16*      D     = phase ? D1 : D0;

        #pragma unroll 1
        for (int h2 = 0; h2 < HH; h2++) {
            const __bf16* Wp0 = W + (size_t)(32*h2 + lr)*DIMC      + 8*lg;
            const __bf16* Wp1 = W + (size_t)(32*h2 + 16 + lr)*DIMC + 8*lg;
            f32x4 a0 = {0.f,0.f,0.f,0.f}, a1 = {0.f,0.f,0.f,0.f};
            #pragma unroll
            for (int ks = 0; ks < 6; ks++) {
                bf16x8 b0 = *(const bf16x8*)(Wp0 + 32*ks);
                bf16x8 b1 = *(const bf16x8*)(Wp1 + 32*ks);
                a0 = mfma16(afr[ks], b0, a0);
                a1 = mfma16(afr[ks], b1, a1);
            }
            if (bias) {
                float bv0 = bias[32*h2 + lr];
                float bv1 = bias[32*h2 + 16 + lr];
                #pragma unroll
                for (int reg = 0; reg < 4; reg++) { a0[reg] += bv0; a1[reg] += bv1; }
            }
            if (nrm) {
                float sc = 1.f;
                if (nrm == 2) sc = __expf(fminf(ls[h2], 4.6051702f)) * 1.4426950408889634f;
                #pragma unroll
                for (int reg = 0; reg < 4; reg++) {
                    float ss = a0[reg]*a0[reg] + a1[reg]*a1[reg];
                    ss += __shfl_xor(ss, 1); ss += __shfl_xor(ss, 2);
                    ss += __shfl_xor(ss, 4); ss += __shfl_xor(ss, 8);
                    float f = sc / fmaxf(sqrtf(ss), 1e-12f);
                    a0[reg] *= f; a1[reg] *= f;
                }
            }
            #pragma unroll
            for (int reg = 0; reg < 4; reg++) {
                int row = m0 + 16*wave + 4*lg + reg;
                D[(size_t)row*DIMC + 32*h2 + lr]      = (__bf16)a0[reg];
                D[(size_t)row*DIMC + 32*h2 + 16 + lr] = (__bf16)a1[reg];
            }
        }
    }
}

// ---------------- proj GEMM: bf16 in, bf16 W direct, f32 out + bias, no LDS ----------------
__global__ __launch_bounds__(256) void gemm_proj(
    const __bf16* __restrict__ A, const __bf16* __restrict__ W,
    const float* __restrict__ bias, float* __restrict__ D)
{
    int m0 = blockIdx.x * 64;
    int t  = threadIdx.x;
    int wave = t >> 6, lane = t & 63, lr = lane & 15, lg = lane >> 4;
    int r = m0 + 16*wave + lr;

    bf16x8 afr[6];
    #pragma unroll
    for (int ks = 0; ks < 6; ks++)
        afr[ks] = *(const bf16x8*)(A + (size_t)r*DIMC + 32*ks + 8*lg);

    #pragma unroll 1
    for (int h2 = 0; h2 < HH; h2++) {
        const __bf16* Wp0 = W + (size_t)(32*h2 + lr)*DIMC      + 8*lg;
        const __bf16* Wp1 = W + (size_t)(32*h2 + 16 + lr)*DIMC + 8*lg;
        f32x4 a0 = {0.f,0.f,0.f,0.f}, a1 = {0.f,0.f,0.f,0.f};
        #pragma unroll
        for (int ks = 0; ks < 6; ks++) {
            bf16x8 b0 = *(const bf16x8*)(Wp0 + 32*ks);
            bf16x8 b1 = *(const bf16x8*)(Wp1 + 32*ks);
            a0 = mfma16(afr[ks], b0, a0);
            a1 = mfma16(afr[ks], b1, a1);
        }
        float bv0 = bias[32*h2 + lr];
        float bv1 = bias[32*h2 + 16 + lr];
        #pragma unroll
        for (int reg = 0; reg < 4; reg++) {
            int row = m0 + 16*wave + 4*lg + reg;
            D[(size_t)row*DIMC + 32*h2 + lr]      = a0[reg] + bv0;
            D[(size_t)row*DIMC + 32*h2 + 16 + lr] = a1[reg] + bv1;
        }
    }
}

// ---------------- fused attention: one block (4 waves) per (b,h), 2 q-tiles/wave ----------------
// swapped QK^T: s = mfma(K,Q) -> lane holds q = q0+lr (fixed), m = 32ks+{0,16}+4lg+reg
#define VT_PITCH 392   // 196 dwords == 4 mod 32: 2-way max on b128 reads
#define P_PITCH  44    // 22 dwords, gcd(22,32)=2: conflict-free across 16 lr lanes
__global__ __launch_bounds__(256, 4) void attn_kernel(
    const __bf16* __restrict__ qb, const __bf16* __restrict__ kb, const __bf16* __restrict__ vb,
    const float* __restrict__ R, const unsigned* __restrict__ mbits,
    __bf16* __restrict__ cross)
{
    __shared__ __bf16 VTs[32*VT_PITCH];   // V^T [d=32][m pitch 392], 25088 B
    __shared__ __bf16 Ps[4*32*P_PITCH];   // per-wave P: rows 16*tile+lr, 11264 B

    int bh = blockIdx.x;
    int b  = bh / HH;
    int h  = bh - b*HH;
    int w  = b & 63;
    int t  = threadIdx.x;

    const __bf16* Kb = kb + ((size_t)b*NN)*DIMC + 32*h;
    const __bf16* Vb = vb + ((size_t)b*NN)*DIMC + 32*h;
    const __bf16* Qb = qb + ((size_t)b*NN)*DIMC + 32*h;

    // stage V^T (consecutive threads -> consecutive m)
    for (int idx = t; idx < NN*4; idx += 256) {
        int part = idx / NN;
        int m    = idx - part*NN;
        union { uint4 u; __bf16 e[8]; } vv;
        vv.u = *(const uint4*)(Vb + (size_t)m*DIMC + 8*part);
        #pragma unroll
        for (int j = 0; j < 8; j++) {
            int d = 8*part + j;
            VTs[d*VT_PITCH + m] = vv.e[j];
        }
    }
    for (int idx = t; idx < 32*9; idx += 256) {
        int d = idx / 9, m = NN + (idx - d*9);
        VTs[d*VT_PITCH + m] = (__bf16)0.f;
    }
    __syncthreads();

    int wave = t >> 6, lane = t & 63, lr = lane & 15, lg = lane >> 4;
    __bf16* Pw = Ps + wave*32*P_PITCH;
    const f32x4 zero = {0.f,0.f,0.f,0.f};

    int p = wave;
    for (int s = 0; s < 3; s++, p += 4) {
        if (p >= 11) break;
        int q00 = 32*p, q01 = 32*p + 16;
        int rc0 = min(q00 + lr, NN-1);
        int rc1 = min(q01 + lr, NN-1);
        bf16x8 qf0 = *(const bf16x8*)(Qb + (size_t)rc0*DIMC + 8*lg);
        bf16x8 qf1 = *(const bf16x8*)(Qb + (size_t)rc1*DIMC + 8*lg);
        const float* Rrow0 = R + ((size_t)h*NN + rc0)*352 + 4*lg;
        const float* Rrow1 = R + ((size_t)h*NN + rc1)*352 + 4*lg;
        uint4 mu0 = *(const uint4*)(mbits + ((size_t)(w*NN + rc0))*16 + 4*lg);
        uint4 mu1 = *(const uint4*)(mbits + ((size_t)(w*NN + rc1))*16 + 4*lg);
        unsigned t0a = mu0.x, t0b = mu0.y, t0c = mu0.z;
        unsigned t1a = mu1.x, t1b = mu1.y, t1c = mu1.z;

        float dsum0 = 0.f, dsum1 = 0.f;
        f32x4 acc00 = zero, acc01 = zero, acc10 = zero, acc11 = zero;

        // prefetch ks = 0
        bf16x8 kfa = *(const bf16x8*)(Kb + (size_t)lr*DIMC + 8*lg);
        bf16x8 kfb = *(const bf16x8*)(Kb + (size_t)(16+lr)*DIMC + 8*lg);
        f32x4 ra0 = *(const f32x4*)(Rrow0);
        f32x4 rb0 = *(const f32x4*)(Rrow0 + 16);
        f32x4 ra1 = *(const f32x4*)(Rrow1);
        f32x4 rb1 = *(const f32x4*)(Rrow1 + 16);

        for (int ks = 0; ks < 11; ks++) {
            // prefetch ks+1
            bf16x8 kfa_n = kfa, kfb_n = kfb;
            f32x4 ra0_n = ra0, rb0_n = rb0, ra1_n = ra1, rb1_n = rb1;
            if (ks < 10) {
                int ma = 32*(ks+1) + lr;
                kfa_n = *(const bf16x8*)(Kb + (size_t)min(ma, NN-1)*DIMC + 8*lg);
                kfb_n = *(const bf16x8*)(Kb + (size_t)min(ma+16, NN-1)*DIMC + 8*lg);
                ra0_n = *(const f32x4*)(Rrow0 + 32*(ks+1));
                rb0_n = *(const f32x4*)(Rrow0 + 32*(ks+1) + 16);
                ra1_n = *(const f32x4*)(Rrow1 + 32*(ks+1));
                rb1_n = *(const f32x4*)(Rrow1 + 32*(ks+1) + 16);
            }

            f32x4 s0a = mfma16(kfa, qf0, zero);
            f32x4 s0b = mfma16(kfb, qf0, zero);
            f32x4 s1a = mfma16(kfa, qf1, zero);
            f32x4 s1b = mfma16(kfb, qf1, zero);

            unsigned nib0 = t0a & 0xFFu;
            t0a = (t0a >> 8) | (t0b << 24); t0b = (t0b >> 8) | (t0c << 24); t0c >>= 8;
            unsigned nib1 = t1a & 0xFFu;
            t1a = (t1a >> 8) | (t1b << 24); t1b = (t1b >> 8) | (t1c << 24); t1c >>= 8;

            // tile 0 softmax numerators
            {
                float pa[4], pb[4];
                #pragma unroll
                for (int r = 0; r < 4; r++) {
                    pa[r] = ((nib0 >> r) & 1)     ? __builtin_amdgcn_exp2f(s0a[r]) * ra0[r] : 0.f;
                    pb[r] = ((nib0 >> (4+r)) & 1) ? __builtin_amdgcn_exp2f(s0b[r]) * rb0[r] : 0.f;
                    dsum0 += pa[r] + pb[r];
                }
                unsigned* pw = (unsigned*)&Pw[lr*P_PITCH + 4*lg];
                pw[0] = pack2(pa[0], pa[1]); pw[1] = pack2(pa[2], pa[3]);
                pw[8] = pack2(pb[0], pb[1]); pw[9] = pack2(pb[2], pb[3]);
            }
            // tile 1
            {
                float pa[4], pb[4];
                #pragma unroll
                for (int r = 0; r < 4; r++) {
                    pa[r] = ((nib1 >> r) & 1)     ? __builtin_amdgcn_exp2f(s1a[r]) * ra1[r] : 0.f;
                    pb[r] = ((nib1 >> (4+r)) & 1) ? __builtin_amdgcn_exp2f(s1b[r]) * rb1[r] : 0.f;
                    dsum1 += pa[r] + pb[r];
                }
                unsigned* pw = (unsigned*)&Pw[(16+lr)*P_PITCH + 4*lg];
                pw[0] = pack2(pa[0], pa[1]); pw[1] = pack2(pa[2], pa[3]);
                pw[8] = pack2(pb[0], pb[1]); pw[9] = pack2(pb[2], pb[3]);
            }

            bf16x8 pa0 = *(const bf16x8*)&Pw[lr*P_PITCH + 8*lg];
            bf16x8 pa1 = *(const bf16x8*)&Pw[(16+lr)*P_PITCH + 8*lg];
            bf16x8 v0  = *(const bf16x8*)&VTs[lr*VT_PITCH      + 32*ks + 8*lg];
            bf16x8 v1  = *(const bf16x8*)&VTs[(16+lr)*VT_PITCH + 32*ks + 8*lg];
            acc00 = mfma16(pa0, v0, acc00);
            acc01 = mfma16(pa0, v1, acc01);
            acc10 = mfma16(pa1, v0, acc10);
            acc11 = mfma16(pa1, v1, acc11);

            kfa = kfa_n; kfb = kfb_n;
            ra0 = ra0_n; rb0 = rb0_n; ra1 = ra1_n; rb1 = rb1_n;
        }

        dsum0 += __shfl_xor(dsum0, 16); dsum0 += __shfl_xor(dsum0, 32);
        dsum1 += __shfl_xor(dsum1, 16); dsum1 += __shfl_xor(dsum1, 32);
        float dinv0 = 1.f / dsum0;
        float dinv1 = 1.f / dsum1;

        #pragma unroll
        for (int reg = 0; reg < 4; reg++) {
            float dv0 = __shfl(dinv0, 4*lg + reg);
            float dv1 = __shfl(dinv1, 4*lg + reg);
            int q0v = q00 + 4*lg + reg;
            int q1v = q01 + 4*lg + reg;
            if (q0v < NN) {
                size_t cb = ((size_t)b*NN + q0v)*DIMC + 32*h;
                cross[cb + lr]      = (__bf16)(acc00[reg] * dv0);
                cross[cb + 16 + lr] = (__bf16)(acc01[reg] * dv0);
            }
            if (q1v < NN) {
                size_t cb = ((size_t)b*NN + q1v)*DIMC + 32*h;
                cross[cb + lr]      = (__bf16)(acc10[reg] * dv1);
                cross[cb + 16 + lr] = (__bf16)(acc11[reg] * dv1);
            }
        }
    }
}

extern "C" void kernel_launch(void* const* d_in, const int* in_sizes, int n_in,
                              void* d_out, int out_size, void* d_ws, size_t ws_size,
                              hipStream_t stream) {
    const float* x           = (const float*)d_in[0];
    const float* y           = (const float*)d_in[1];
    const float* mask        = (const float*)d_in[2];
    const float* qkv1_w      = (const float*)d_in[3];
    const float* qkv2_w      = (const float*)d_in[4];
    const float* v1_bias     = (const float*)d_in[6];
    const float* q2_bias     = (const float*)d_in[7];
    const float* logit_scale = (const float*)d_in[9];
    const float* cpb_w1      = (const float*)d_in[10];
    const float* cpb_b1      = (const float*)d_in[11];
    const float* cpb_w2      = (const float*)d_in[12];
    const float* proj_w      = (const float*)d_in[13];
    const float* proj_b      = (const float*)d_in[14];
    const float* rel_table   = (const float*)d_in[15];
    const int*   rp_index    = (const int*)d_in[16];

    char* ws = (char*)d_ws;
    float*    table  = (float*)(ws + OFF_TABLE);
    float*    R      = (float*)(ws + OFF_R);
    unsigned* mb     = (unsigned*)(ws + OFF_MB);
    __bf16*   q_bf   = (__bf16*)(ws + OFF_QB);
    __bf16*   k_bf   = (__bf16*)(ws + OFF_KB);
    __bf16*   v_bf   = (__bf16*)(ws + OFF_VB);
    __bf16*   crossb = (__bf16*)(ws + OFF_CROSS);
    __bf16*   wbf    = (__bf16*)(ws + OFF_WB);

    __bf16* w_k    = wbf + 192*DIMC;        // qkv1 rows 192..383
    __bf16* w_v    = wbf + 384*DIMC;        // qkv1 rows 384..575
    __bf16* w_q    = wbf + 576*DIMC;        // qkv2 rows 0..191
    __bf16* w_proj = wbf + 1152*DIMC;

    cpb_table_kernel<<<2197, 256, 0, stream>>>(rel_table, cpb_w1, cpb_b1, cpb_w2, table);
    r_kernel<<<(HH*NN*352 + 255)/256, 256, 0, stream>>>(table, rp_index, R);
    mbits_kernel<<<(64*NN*4)/256, 256, 0, stream>>>(mask, mb);
    wcvt_kernel<<<(258048/4 + 255)/256, 256, 0, stream>>>(qkv1_w, qkv2_w, proj_w, wbf);
    // x -> k (norm, no bias), v (+v1_bias, no norm)
    gemm_f32in<<<MM/64, 256, 0, stream>>>(x, logit_scale,
                                          w_k, nullptr, 1, k_bf,
                                          w_v, v1_bias, 0, v_bf);
    // y -> q (+q2_bias, norm+scale*log2e)
    gemm_f32in<<<MM/64, 256, 0, stream>>>(y, logit_scale,
                                          w_q, q2_bias, 2, q_bf,
                                          nullptr, nullptr, 0, nullptr);

    attn_kernel<<<BB*HH, 256, 0, stream>>>(q_bf, k_bf, v_bf, R, mb, crossb);

    gemm_proj<<<MM/64, 256, 0, stream>>>(crossb, w_proj, proj_b, (float*)d_out);
}